// Round 3
// baseline (274.874 us; speedup 1.0000x reference)
//
#include <hip/hip_runtime.h>
#include <hip/hip_bf16.h>
#include <stdint.h>

// Problem constants (from reference)
#define N_TOKENS   4096
#define IN_FEAT    1024
#define OUT_FEAT   2048
#define NUM_EXPERT 16

// GEMM tiling
#define BM 128
#define BN 128
#define BK 32
#define NT (IN_FEAT / BK)     // 32 K-steps
#define MAX_TILES 48          // sum_e ceil(cnt_e/128) <= 47
#define MAX_ROWS  6144        // padded sorted rows upper bound (<=6016)

typedef __bf16 bf16x8 __attribute__((ext_vector_type(8)));
typedef float  f32x4  __attribute__((ext_vector_type(4)));
typedef unsigned short us8 __attribute__((ext_vector_type(8)));  // 16B

__device__ __forceinline__ unsigned short f32_to_bf16_rne(float f) {
  union { float f; uint32_t u; } v; v.f = f;
  uint32_t u = v.u;
  u += 0x7fffu + ((u >> 16) & 1u);   // round-nearest-even
  return (unsigned short)(u >> 16);
}

// async global->LDS, 16B per lane. LDS base wave-uniform; lane i lands at
// base + i*16. Source address is PER-LANE.
__device__ __forceinline__ void async_copy16(const void* g, void* l) {
  __builtin_amdgcn_global_load_lds(
      (const __attribute__((address_space(1))) unsigned int*)g,
      (__attribute__((address_space(3))) unsigned int*)l, 16, 0, 0);
}

// ---------------------------------------------------------------------------
// Kernel 1: routing setup (single block). Histogram, padded prefix, scatter.
// ---------------------------------------------------------------------------
__global__ void k_setup(const int* __restrict__ gate,
                        int* __restrict__ pstart,     // [16] padded seg start
                        int* __restrict__ tile_e,     // [MAX_TILES]
                        int* __restrict__ tile_m,     // [MAX_TILES]
                        int* __restrict__ row_token)  // [MAX_ROWS], -1 = pad
{
  __shared__ int cnt[NUM_EXPERT];
  __shared__ int cur[NUM_EXPERT];
  __shared__ int ps[NUM_EXPERT];
  const int tid = threadIdx.x;
  if (tid < NUM_EXPERT) { cnt[tid] = 0; cur[tid] = 0; }
  __syncthreads();
  for (int b = tid; b < N_TOKENS; b += 256) atomicAdd(&cnt[gate[b]], 1);
  for (int r = tid; r < MAX_ROWS; r += 256) row_token[r] = -1;
  __syncthreads();
  if (tid == 0) {
    int p = 0, tot = 0;
    for (int e = 0; e < NUM_EXPERT; ++e) {
      ps[e] = p; pstart[e] = p;
      int nt = (cnt[e] + BM - 1) / BM;
      for (int t = 0; t < nt; ++t) { tile_e[tot] = e; tile_m[tot] = t; ++tot; }
      p += nt * BM;
    }
    for (int s = tot; s < MAX_TILES; ++s) { tile_e[s] = -1; tile_m[s] = 0; }
  }
  __syncthreads();
  for (int b = tid; b < N_TOKENS; b += 256) {
    int e = gate[b];
    int pos = atomicAdd(&cur[e], 1);
    row_token[ps[e] + pos] = b;
  }
}

// ---------------------------------------------------------------------------
// Kernel 2: gather x into sorted padded order + cast to bf16; pads -> zeros.
// ---------------------------------------------------------------------------
__global__ void k_gather_x(const float4* __restrict__ x,
                           const int* __restrict__ row_token,
                           us8* __restrict__ xs) {
  const int r = blockIdx.x * 2 + (threadIdx.x >> 7);
  const int c = threadIdx.x & 127;
  const int tok = row_token[r];
  us8 o;
  if (tok >= 0) {
    float4 a = x[tok * 256 + c * 2];
    float4 b = x[tok * 256 + c * 2 + 1];
    o[0] = f32_to_bf16_rne(a.x); o[1] = f32_to_bf16_rne(a.y);
    o[2] = f32_to_bf16_rne(a.z); o[3] = f32_to_bf16_rne(a.w);
    o[4] = f32_to_bf16_rne(b.x); o[5] = f32_to_bf16_rne(b.y);
    o[6] = f32_to_bf16_rne(b.z); o[7] = f32_to_bf16_rne(b.w);
  } else {
    o = (us8)0;
  }
  xs[r * 128 + c] = o;
}

// ---------------------------------------------------------------------------
// Kernel 3: grouped GEMM.
// Round-2 restructure (BW-wall on staged operand bytes, 6.5 TB/s fabric):
//  * A is no longer LDS-staged: each wave loads its A fragments directly
//    global->VGPR (16B contiguous per mi; same fragment mapping the LDS path
//    used). Cuts DMA instrs 6->4 and ds_reads 12->8 per thread-step.
//  * Block->XCD swizzle groups all 16 n-tiles of a slot PAIR (same expert,
//    adjacent m-tiles) onto one XCD (dispatch round-robin id%8): A panels
//    (6 slots x 256KB) become L2-resident per XCD; B-panel sharers co-XCD.
//  * B (fp32) stays LDS-DMA double-buffered with counted vmcnt (never 0 in
//    the main loop); fp32->bf16 convert in regs between ds_read and MFMA.
//   B LDS: slot(r,c) = r*8 + (c ^ (r&7)), c = 16B chunk 0..7 (2-way = free).
// ---------------------------------------------------------------------------
__global__ void __launch_bounds__(256, 3)
k_gemm(const unsigned short* __restrict__ xs,   // [MAX_ROWS][IN_FEAT] bf16
       const float* __restrict__ w,             // [E][OUT_FEAT][IN_FEAT] fp32
       const int* __restrict__ pstart,
       const int* __restrict__ tile_e,
       const int* __restrict__ tile_m,
       const int* __restrict__ row_token,
       float* __restrict__ out) {
  __shared__ f32x4 Bs[2][1024];   // 2 x 16 KB (double-buffered)
  __shared__ int rowtok_s[BM];

  // --- XCD-aware block swizzle (bijective mixed-radix over 768 ids) ---
  // id = r + 8*(q3 + 3*(sub + 2*xt)), r in 0..7, q3 in 0..2, sub in 0..1,
  // xt in 0..15.  slot = 2*(r + 8*q3) + sub  (0..47), n-tile = xt.
  // All 16 xt of a slot-pair share dispatch id%8 == r -> same XCD.
  const int id  = blockIdx.y * 16 + blockIdx.x;
  const int r_  = id & 7;
  const int m_  = id >> 3;        // 0..95
  const int q3  = m_ % 3;
  const int n_  = m_ / 3;         // 0..31
  const int sub = n_ & 1;
  const int xt  = n_ >> 1;        // n-tile index 0..15

  const int slot = 2 * (r_ + 8 * q3) + sub;
  const int e = tile_e[slot];
  if (e < 0) return;
  const int seg0 = pstart[e] + tile_m[slot] * BM;
  const int n0 = xt * BN;

  const int tid  = threadIdx.x;
  const int wid  = tid >> 6;
  const int lane = tid & 63;
  const int lr   = lane & 15;
  const int quad = lane >> 4;
  const int wm   = (wid >> 1) * 64;   // wave m-offset in tile
  const int wn   = (wid & 1) * 64;    // wave n-offset in tile

  if (tid < BM) rowtok_s[tid] = row_token[seg0 + tid];

  // B staging source (swizzled chunk is round-invariant):
  const int cB = (tid & 7) ^ ((tid >> 3) & 7);   // B chunk (16B) within row
  const float* bgp = w + (size_t)e * OUT_FEAT * IN_FEAT
                       + (size_t)(n0 + (tid >> 3)) * IN_FEAT + cB * 4;

  // A direct-load base: lane (lr,quad) of this wave reads
  // row = seg0 + wm + mi*16 + lr, cols [k0 + quad*8, +8)  (16B, aligned).
  const unsigned short* ap =
      xs + (size_t)(seg0 + wm + lr) * IN_FEAT + quad * 8;

  f32x4 acc[4][4];
  const f32x4 z = {0.f, 0.f, 0.f, 0.f};
#pragma unroll
  for (int i = 0; i < 4; ++i)
#pragma unroll
    for (int j = 0; j < 4; ++j) acc[i][j] = z;

  // 4 async B-DMA per thread per stage (4 KB per instr per block).
  auto stageB = [&](int t, int b) {
    const int k0 = t * BK;
    async_copy16(bgp + k0,                 Bs[b] + wid * 64);         // B t=0
    async_copy16(bgp + 32 * IN_FEAT + k0,  Bs[b] + 256 + wid * 64);   // B t=1
    async_copy16(bgp + 64 * IN_FEAT + k0,  Bs[b] + 512 + wid * 64);   // B t=2
    async_copy16(bgp + 96 * IN_FEAT + k0,  Bs[b] + 768 + wid * 64);   // B t=3
  };
  // 4 x global_load_dwordx4 (A fragments for step t) into named regs.
  auto loadA = [&](int t, bf16x8* dst) {
#pragma unroll
    for (int mi = 0; mi < 4; ++mi)
      dst[mi] = *(const bf16x8*)(ap + (size_t)mi * 16 * IN_FEAT + t * BK);
  };

  bf16x8 afA[4], afB[4];    // double-buffered A fragments (static indexing)

  stageB(0, 0);             // 4 DMA in flight
  loadA(0, afA);            // 4 A loads in flight (compiler-tracked)

  // Publish rowtok_s (ds_write from threads 0..127) before the raw-s_barrier
  // pipeline (raw s_barrier does not drain lgkmcnt).
  asm volatile("s_waitcnt lgkmcnt(0)" ::: "memory");
  __builtin_amdgcn_s_barrier();

  // One pipeline step. afc = A frags for step t (ready), afn = prefetch dst.
  auto step = [&](int t, bf16x8* afc, bf16x8* afn) {
    const int buf = t & 1;
    if (t + 1 < NT) {
      stageB(t + 1, buf ^ 1);     // 4 DMA (newest)
      loadA(t + 1, afn);          // 4 A loads (newest)
      // Wait until only the 8 just-issued remain -> stage-t B-DMA (and all
      // older VMEM) landed. Never drains to 0 in the main loop.
      asm volatile("s_waitcnt vmcnt(8)" ::: "memory");
    } else {
      asm volatile("s_waitcnt vmcnt(0)" ::: "memory");
    }
    __builtin_amdgcn_s_barrier();   // all waves' stage-t B visible
    asm volatile("" ::: "memory");

    bf16x8 bf[4];
#pragma unroll
    for (int ni = 0; ni < 4; ++ni) {
      const int n = wn + ni * 16 + lr;
      f32x4 c0 = Bs[buf][n * 8 + ((2 * quad)     ^ (n & 7))];
      f32x4 c1 = Bs[buf][n * 8 + ((2 * quad + 1) ^ (n & 7))];
      bf16x8 b;
      b[0] = (__bf16)c0[0]; b[1] = (__bf16)c0[1];
      b[2] = (__bf16)c0[2]; b[3] = (__bf16)c0[3];
      b[4] = (__bf16)c1[0]; b[5] = (__bf16)c1[1];
      b[6] = (__bf16)c1[2]; b[7] = (__bf16)c1[3];
      bf[ni] = b;
    }
#pragma unroll
    for (int mi = 0; mi < 4; ++mi)
#pragma unroll
      for (int ni = 0; ni < 4; ++ni)
        acc[mi][ni] = __builtin_amdgcn_mfma_f32_16x16x32_bf16(
            afc[mi], bf[ni], acc[mi][ni], 0, 0, 0);

    asm volatile("" ::: "memory");
    __builtin_amdgcn_s_barrier();   // reads of Bs[buf] done before overwrite
  };

  for (int t = 0; t < NT; t += 2) {   // NT even; 2x unroll keeps A regs named
    step(t,     afA, afB);
    step(t + 1, afB, afA);
  }

  // Epilogue: C/D layout col=lane&15, row=quad*4+reg (verified m89/m91).
#pragma unroll
  for (int mi = 0; mi < 4; ++mi) {
    const int mb = wm + mi * 16 + quad * 4;
    const int t0 = rowtok_s[mb + 0];
    const int t1 = rowtok_s[mb + 1];
    const int t2 = rowtok_s[mb + 2];
    const int t3 = rowtok_s[mb + 3];
#pragma unroll
    for (int ni = 0; ni < 4; ++ni) {
      const int n = n0 + wn + ni * 16 + lr;
      f32x4 c = acc[mi][ni];
      if (t0 >= 0) out[(size_t)t0 * OUT_FEAT + n] = c[0];
      if (t1 >= 0) out[(size_t)t1 * OUT_FEAT + n] = c[1];
      if (t2 >= 0) out[(size_t)t2 * OUT_FEAT + n] = c[2];
      if (t3 >= 0) out[(size_t)t3 * OUT_FEAT + n] = c[3];
    }
  }
}

// ---------------------------------------------------------------------------
extern "C" void kernel_launch(void* const* d_in, const int* in_sizes, int n_in,
                              void* d_out, int out_size, void* d_ws, size_t ws_size,
                              hipStream_t stream) {
  const float* x    = (const float*)d_in[0];
  const int*   gate = (const int*)d_in[1];
  const float* w    = (const float*)d_in[2];
  float* out = (float*)d_out;

  // workspace layout (~13 MB)
  char* ws = (char*)d_ws;
  unsigned short* xs = (unsigned short*)ws;                        // 12 MB
  int* row_token = (int*)(ws + 12582912);                          // 24 KB
  int* pstart = row_token + MAX_ROWS;
  int* tile_e = pstart + NUM_EXPERT;
  int* tile_m = tile_e + MAX_TILES;

  k_setup<<<1, 256, 0, stream>>>(gate, pstart, tile_e, tile_m, row_token);
  k_gather_x<<<MAX_ROWS / 2, 256, 0, stream>>>((const float4*)x, row_token,
                                               (us8*)xs);
  dim3 g(OUT_FEAT / BN, MAX_TILES);
  k_gemm<<<g, 256, 0, stream>>>(xs, w, pstart, tile_e, tile_m, row_token, out);
}

// Round 4
// 260.437 us; speedup vs baseline: 1.0554x; 1.0554x over previous
//
#include <hip/hip_runtime.h>
#include <hip/hip_bf16.h>
#include <stdint.h>

// Problem constants (from reference)
#define N_TOKENS   4096
#define IN_FEAT    1024
#define OUT_FEAT   2048
#define NUM_EXPERT 16

#define BM 128                // row-padding quantum (routing)
#define BK 32                 // K-slice per pipeline step
#define NT (IN_FEAT / BK)     // 32 K-steps
#define BNW 128               // per-block n-window (weight panel width)
#define GROWS 512             // rows processed per group (8 waves x 64 rows)
#define MAX_ROWS  6144        // padded sorted rows upper bound (<=6016)

typedef __bf16 bf16x8 __attribute__((ext_vector_type(8)));
typedef float  f32x4  __attribute__((ext_vector_type(4)));
typedef unsigned short us8 __attribute__((ext_vector_type(8)));  // 16B

__device__ __forceinline__ unsigned short f32_to_bf16_rne(float f) {
  union { float f; uint32_t u; } v; v.f = f;
  uint32_t u = v.u;
  u += 0x7fffu + ((u >> 16) & 1u);   // round-nearest-even
  return (unsigned short)(u >> 16);
}

// async global->LDS, 16B per lane. LDS dest is wave-uniform base + lane*16;
// source address is PER-LANE (so we pre-swizzle the source).
__device__ __forceinline__ void async_copy16(const void* g, void* l) {
  __builtin_amdgcn_global_load_lds(
      (const __attribute__((address_space(1))) unsigned int*)g,
      (__attribute__((address_space(3))) unsigned int*)l, 16, 0, 0);
}

// ---------------------------------------------------------------------------
// Kernel 1: routing setup (single block). Histogram, padded prefix, scatter.
// pstart[17]: padded segment starts, pstart[16] = total padded rows.
// ---------------------------------------------------------------------------
__global__ void k_setup(const int* __restrict__ gate,
                        int* __restrict__ pstart,     // [17]
                        int* __restrict__ row_token)  // [MAX_ROWS], -1 = pad
{
  __shared__ int cnt[NUM_EXPERT];
  __shared__ int cur[NUM_EXPERT];
  __shared__ int ps[NUM_EXPERT];
  const int tid = threadIdx.x;
  if (tid < NUM_EXPERT) { cnt[tid] = 0; cur[tid] = 0; }
  __syncthreads();
  for (int b = tid; b < N_TOKENS; b += 256) atomicAdd(&cnt[gate[b]], 1);
  for (int r = tid; r < MAX_ROWS; r += 256) row_token[r] = -1;
  __syncthreads();
  if (tid == 0) {
    int p = 0;
    for (int e = 0; e < NUM_EXPERT; ++e) {
      ps[e] = p; pstart[e] = p;
      p += ((cnt[e] + BM - 1) / BM) * BM;
    }
    pstart[NUM_EXPERT] = p;
  }
  __syncthreads();
  for (int b = tid; b < N_TOKENS; b += 256) {
    int e = gate[b];
    int pos = atomicAdd(&cur[e], 1);
    row_token[ps[e] + pos] = b;
  }
}

// ---------------------------------------------------------------------------
// Kernel 2: gather x into sorted padded order + cast to bf16; pads -> zeros.
// ---------------------------------------------------------------------------
__global__ void k_gather_x(const float4* __restrict__ x,
                           const int* __restrict__ row_token,
                           us8* __restrict__ xs) {
  const int r = blockIdx.x * 2 + (threadIdx.x >> 7);
  const int c = threadIdx.x & 127;
  const int tok = row_token[r];
  us8 o;
  if (tok >= 0) {
    float4 a = x[tok * 256 + c * 2];
    float4 b = x[tok * 256 + c * 2 + 1];
    o[0] = f32_to_bf16_rne(a.x); o[1] = f32_to_bf16_rne(a.y);
    o[2] = f32_to_bf16_rne(a.z); o[3] = f32_to_bf16_rne(a.w);
    o[4] = f32_to_bf16_rne(b.x); o[5] = f32_to_bf16_rne(b.y);
    o[6] = f32_to_bf16_rne(b.z); o[7] = f32_to_bf16_rne(b.w);
  } else {
    o = (us8)0;
  }
  xs[r * 128 + c] = o;
}

// ---------------------------------------------------------------------------
// Kernel 3: grouped GEMM, W-STREAMING / X-RESIDENT.
// Grid = 16 experts x 16 n-windows = 256 blocks (1/CU), 512 threads (8 waves).
// Each block owns weight panel W[e][nwin:nwin+128][:] and streams it from HBM
// EXACTLY ONCE (B total = 128 MB, the minimum). Token activations (xs, bf16,
// 12 MB) are read direct global->VGPR; expert-e blocks share id%8=e%8 so the
// panel is XCD-L2-resident. Rows processed in 512-row groups: wave w owns
// rows [w*64, w*64+64) of the group (disjoint -> no duplicate loads).
// B LDS layout: slot(r,c) = r*8 + (c ^ (r&7)), c = 16B chunk 0..7; staged via
// pre-swizzled-source DMA (linear dest), double-buffered, counted vmcnt(6).
// Out-of-segment rows: A clamped to row 0 (garbage acc), stores guarded by
// rowtok == -1.  fp32->bf16 convert in regs between ds_read and MFMA.
// ---------------------------------------------------------------------------
__global__ void __launch_bounds__(512, 2)
k_gemm(const unsigned short* __restrict__ xs,   // [MAX_ROWS][IN_FEAT] bf16
       const float* __restrict__ w,             // [E][OUT_FEAT][IN_FEAT] fp32
       const int* __restrict__ pstart,          // [17]
       const int* __restrict__ row_token,
       float* __restrict__ out) {
  __shared__ f32x4 Bs[2][1024];      // 2 x 16 KB (double-buffered k-slice)
  __shared__ int rowtok_s[GROWS];    // 2 KB

  const int e    = blockIdx.x;                 // id%8 = e%8 -> XCD grouping
  const int nwin = blockIdx.y * BNW;
  const int seg0 = pstart[e];
  const int seg_len = pstart[e + 1] - seg0;    // padded (multiple of 128)
  if (seg_len <= 0) return;                    // block-uniform

  const int tid  = threadIdx.x;
  const int wid  = tid >> 6;        // 0..7 -> wave m-slice (64 rows)
  const int lane = tid & 63;
  const int lr   = lane & 15;
  const int quad = lane >> 4;

  // B staging source: thread covers B-row rB = tid>>3 (+64 on round 1),
  // source chunk pre-swizzled so linear-dest DMA realizes slot(r,c)=r*8+(c^(r&7)).
  const int rB = tid >> 3;                        // 0..63
  const int cB = (tid & 7) ^ (rB & 7);            // 16B chunk within 128B row
  const float* bgp = w + (size_t)e * OUT_FEAT * IN_FEAT
                       + (size_t)(nwin + rB) * IN_FEAT + cB * 4;

  auto stageB = [&](int t, int b) {
    const int k0 = t * BK;
    async_copy16(bgp + k0,                Bs[b] +       wid * 64);  // rows 0..63
    async_copy16(bgp + 64 * IN_FEAT + k0, Bs[b] + 512 + wid * 64);  // rows 64..127
  };

  const int nGroups = (seg_len + GROWS - 1) / GROWS;   // usually 1

  for (int g = 0; g < nGroups; ++g) {
    __syncthreads();   // protect rowtok_s/Bs reuse vs previous group epilogue

    // rowtok for this group (one row per thread).
    {
      const int grow = g * GROWS + tid;
      rowtok_s[tid] = (grow < seg_len) ? row_token[seg0 + grow] : -1;
    }

    // Per-mi A base pointers (k-invariant; clamp out-of-segment rows to 0).
    const unsigned short* apm[4];
#pragma unroll
    for (int mi = 0; mi < 4; ++mi) {
      const int grow = g * GROWS + wid * 64 + mi * 16 + lr;
      const int arow = (grow < seg_len) ? grow : 0;
      apm[mi] = xs + (size_t)(seg0 + arow) * IN_FEAT + quad * 8;
    }

    auto loadA = [&](int t, bf16x8* dst) {
#pragma unroll
      for (int mi = 0; mi < 4; ++mi)
        dst[mi] = *(const bf16x8*)(apm[mi] + t * BK);
    };

    f32x4 acc[4][8];
    const f32x4 z = {0.f, 0.f, 0.f, 0.f};
#pragma unroll
    for (int i = 0; i < 4; ++i)
#pragma unroll
      for (int j = 0; j < 8; ++j) acc[i][j] = z;

    bf16x8 afA[4], afB[4];     // double-buffered A frags (static indexing)

    stageB(0, 0);              // 2 DMA in flight
    loadA(0, afA);             // 4 A loads in flight (compiler-tracked)

    // Publish rowtok_s before the raw-barrier pipeline.
    asm volatile("s_waitcnt lgkmcnt(0)" ::: "memory");
    __builtin_amdgcn_s_barrier();

    auto step = [&](int t, bf16x8* afc, bf16x8* afn) {
      const int buf = t & 1;
      if (t + 1 < NT) {
        stageB(t + 1, buf ^ 1);      // 2 DMA (newest)
        loadA(t + 1, afn);           // 4 A loads (newest)
        // all but the 6 just-issued retired -> stage-t B landed.
        asm volatile("s_waitcnt vmcnt(6)" ::: "memory");
      } else {
        asm volatile("s_waitcnt vmcnt(0)" ::: "memory");
      }
      __builtin_amdgcn_s_barrier();   // stage-t B visible to all waves
      asm volatile("" ::: "memory");

      bf16x8 bf[8];
#pragma unroll
      for (int ni = 0; ni < 8; ++ni) {
        const int n = ni * 16 + lr;
        f32x4 c0 = Bs[buf][n * 8 + ((2 * quad)     ^ (n & 7))];
        f32x4 c1 = Bs[buf][n * 8 + ((2 * quad + 1) ^ (n & 7))];
        bf16x8 b;
        b[0] = (__bf16)c0[0]; b[1] = (__bf16)c0[1];
        b[2] = (__bf16)c0[2]; b[3] = (__bf16)c0[3];
        b[4] = (__bf16)c1[0]; b[5] = (__bf16)c1[1];
        b[6] = (__bf16)c1[2]; b[7] = (__bf16)c1[3];
        bf[ni] = b;
      }
#pragma unroll
      for (int mi = 0; mi < 4; ++mi)
#pragma unroll
        for (int ni = 0; ni < 8; ++ni)
          acc[mi][ni] = __builtin_amdgcn_mfma_f32_16x16x32_bf16(
              afc[mi], bf[ni], acc[mi][ni], 0, 0, 0);

      asm volatile("" ::: "memory");
      __builtin_amdgcn_s_barrier();   // reads of Bs[buf] done before overwrite
    };

    for (int t = 0; t < NT; t += 2) {   // NT even; keeps A regs named
      step(t,     afA, afB);
      step(t + 1, afB, afA);
    }

    // Epilogue: C/D layout col=lane&15, row=quad*4+reg (verified m89/m91).
#pragma unroll
    for (int mi = 0; mi < 4; ++mi) {
      const int mb = wid * 64 + mi * 16 + quad * 4;
      const int t0 = rowtok_s[mb + 0];
      const int t1 = rowtok_s[mb + 1];
      const int t2 = rowtok_s[mb + 2];
      const int t3 = rowtok_s[mb + 3];
#pragma unroll
      for (int ni = 0; ni < 8; ++ni) {
        const int n = nwin + ni * 16 + lr;
        f32x4 c = acc[mi][ni];
        if (t0 >= 0) out[(size_t)t0 * OUT_FEAT + n] = c[0];
        if (t1 >= 0) out[(size_t)t1 * OUT_FEAT + n] = c[1];
        if (t2 >= 0) out[(size_t)t2 * OUT_FEAT + n] = c[2];
        if (t3 >= 0) out[(size_t)t3 * OUT_FEAT + n] = c[3];
      }
    }
  }
}

// ---------------------------------------------------------------------------
extern "C" void kernel_launch(void* const* d_in, const int* in_sizes, int n_in,
                              void* d_out, int out_size, void* d_ws, size_t ws_size,
                              hipStream_t stream) {
  const float* x    = (const float*)d_in[0];
  const int*   gate = (const int*)d_in[1];
  const float* w    = (const float*)d_in[2];
  float* out = (float*)d_out;

  // workspace layout (~13 MB)
  char* ws = (char*)d_ws;
  unsigned short* xs = (unsigned short*)ws;                        // 12 MB
  int* row_token = (int*)(ws + 12582912);                          // 24 KB
  int* pstart = row_token + MAX_ROWS;                              // 17 ints

  k_setup<<<1, 256, 0, stream>>>(gate, pstart, row_token);
  k_gather_x<<<MAX_ROWS / 2, 256, 0, stream>>>((const float4*)x, row_token,
                                               (us8*)xs);
  dim3 g(NUM_EXPERT, OUT_FEAT / BNW);   // (16, 16) = 256 blocks = 1/CU
  k_gemm<<<g, 512, 0, stream>>>(xs, w, pstart, row_token, out);
}